// Round 5
// baseline (102.338 us; speedup 1.0000x reference)
//
#include <hip/hip_runtime.h>

// Point-splat renderer, round 5:
//  - custom uint4 fill kernel (rocclr fillBuffer measured 107 GB/s / 39 us on
//    a 4 MB memset -- pathological; ours is one coalesced pass, ~2 us)
//  - descending-index chunk passes with an inline u8 chunk-tag array instead
//    of rebuilt bitmasks: after atomicMax, plain-store tag[pix]=chunk. Racy
//    stores are safe: every stored value is a true "covered by chunk<=c"
//    claim (chunk c indices all beat chunk>c indices), so false skips are
//    impossible; lost updates only cost extra atomics. Tags from pass k are
//    visible to pass k+1 via end-of-dispatch L2 writeback (stream order).
//  - 8 chunks (n/32,n/32,n/16,n/16,n/8,n/8,n/4,5n/16): expected atomics
//    ~0.21n vs 0.25n with round-4's 5 chunks (continuous floor ~0.17n).
//
// Inputs: d_in[0] positions (N*3 f32), d_in[1] colors (N*3 f32),
//         d_in[2] camera_pose (16 f32), d_in[3] intrinsics (9 f32),
//         d_in[4] H (1 int), d_in[5] W (1 int)
// Output: (1,3,H,W) f32 flat.

__global__ void fill_ff_kernel(uint4* __restrict__ p, int n4) {
    int i = blockIdx.x * blockDim.x + threadIdx.x;
    uint4 v = make_uint4(0xFFFFFFFFu, 0xFFFFFFFFu, 0xFFFFFFFFu, 0xFFFFFFFFu);
    for (; i < n4; i += gridDim.x * blockDim.x) p[i] = v;
}

__global__ void proj_kernel(const float* __restrict__ pos,
                            const float* __restrict__ pose,
                            const float* __restrict__ intr,
                            const int* __restrict__ Hp,
                            const int* __restrict__ Wp,
                            int* __restrict__ winner,
                            unsigned char* __restrict__ tag,
                            int use_tag, int chunk, int start, int end) {
    int i = start + blockIdx.x * blockDim.x + threadIdx.x;
    if (i >= end) return;

    float px = pos[3 * i + 0];
    float py = pos[3 * i + 1];
    float pz = pos[3 * i + 2];

    // pc = R * p + t
    float x = pose[0] * px + pose[1] * py + pose[2]  * pz + pose[3];
    float y = pose[4] * px + pose[5] * py + pose[6]  * pz + pose[7];
    float z = pose[8] * px + pose[9] * py + pose[10] * pz + pose[11];

    float fx = intr[0], cx = intr[2];
    float fy = intr[4], cy = intr[5];

    float u = fx * x / z + cx;
    float v = fy * y / z + cy;

    int xi = (int)u;   // trunc toward zero == numpy astype(int32)
    int yi = (int)v;

    int W = *Wp, H = *Hp;
    if (xi >= 0 && xi < W && yi >= 0 && yi < H) {
        int pix = yi * W + xi;
        if (use_tag) {
            // skip iff covered by a strictly higher-priority (lower id) chunk
            if (tag[pix] < (unsigned char)chunk) return;
            atomicMax(&winner[pix], i);
            tag[pix] = (unsigned char)chunk;   // racy, monotone-safe
        } else {
            atomicMax(&winner[pix], i);
        }
    }
}

__global__ void paint_kernel(const int* __restrict__ winner,
                             const float* __restrict__ colors,
                             float* __restrict__ out,
                             int HW) {
    int p = blockIdx.x * blockDim.x + threadIdx.x;
    if (p >= HW) return;

    int w = winner[p];
    float r = 0.0f, g = 0.0f, b = 0.0f;
    if (w >= 0) {
        r = colors[3 * w + 0];
        g = colors[3 * w + 1];
        b = colors[3 * w + 2];
        r = fminf(fmaxf(r, 0.0f), 1.0f);
        g = fminf(fmaxf(g, 0.0f), 1.0f);
        b = fminf(fmaxf(b, 0.0f), 1.0f);
    }
    out[p] = r;
    out[HW + p] = g;
    out[2 * HW + p] = b;
}

extern "C" void kernel_launch(void* const* d_in, const int* in_sizes, int n_in,
                              void* d_out, int out_size, void* d_ws, size_t ws_size,
                              hipStream_t stream) {
    const float* positions = (const float*)d_in[0];
    const float* colors    = (const float*)d_in[1];
    const float* pose      = (const float*)d_in[2];
    const float* intr      = (const float*)d_in[3];
    const int*   Hp        = (const int*)d_in[4];
    const int*   Wp        = (const int*)d_in[5];
    float* out = (float*)d_out;

    int n  = in_sizes[0] / 3;       // number of points
    int HW = out_size / 3;          // H*W pixels

    int* winner = (int*)d_ws;
    unsigned char* tag = (unsigned char*)(winner + HW);   // HW bytes
    size_t need = (size_t)HW * 5;                          // winner + tag

    const int block = 256;

    if (ws_size < need || n < 4096 || (HW & 15)) {
        // Fallback: memset winner, single full atomic pass.
        hipMemsetAsync(winner, 0xFF, (size_t)HW * sizeof(int), stream);
        int grid = (n + block - 1) / block;
        proj_kernel<<<grid, block, 0, stream>>>(positions, pose, intr, Hp, Wp,
                                                winner, (unsigned char*)0, 0, 0,
                                                0, n);
    } else {
        // winner = -1, tag = 0xFF (both are all-FF bytes), one vector fill.
        int n4 = (HW * 5) / 16;
        int fgrid = min((n4 + block - 1) / block, 2048);
        fill_ff_kernel<<<fgrid, block, 0, stream>>>((uint4*)d_ws, n4);

        // Descending chunks: sizes n/32,n/32,n/16,n/16,n/8,n/8,n/4,rest.
        long long ln = n;
        int bounds[9];
        bounds[0] = n;
        bounds[1] = (int)(ln * 31 / 32);
        bounds[2] = (int)(ln * 30 / 32);
        bounds[3] = (int)(ln * 28 / 32);
        bounds[4] = (int)(ln * 26 / 32);
        bounds[5] = (int)(ln * 22 / 32);
        bounds[6] = (int)(ln * 18 / 32);
        bounds[7] = (int)(ln * 10 / 32);
        bounds[8] = 0;

        for (int k = 0; k < 8; ++k) {
            int end = bounds[k], start = bounds[k + 1];
            int cnt = end - start;
            if (cnt <= 0) continue;
            int grid = (cnt + block - 1) / block;
            proj_kernel<<<grid, block, 0, stream>>>(positions, pose, intr, Hp, Wp,
                                                    winner, tag, 1, k, start, end);
        }
    }

    int grid2 = (HW + block - 1) / block;
    paint_kernel<<<grid2, block, 0, stream>>>(winner, colors, out, HW);
}

// Round 6
// 102.219 us; speedup vs baseline: 1.0012x; 1.0012x over previous
//
#include <hip/hip_runtime.h>

// Point-splat renderer, round 6: round-4 bitmask structure + round-5 fast fill.
//
//  - winner[pix] = max point index (memory-side atomicMax; measured ~27G/s,
//    proj time ~ atomic count). Descending-index chunks; between chunks a
//    128 KB coverage bitmask (bit p = winner[p]>=0) is rebuilt COALESCED.
//    During a pass the mask is read-only -> stays L1/L2 resident (round 5
//    showed scattered in-pass metadata writes thrash L2 across XCDs).
//  - custom uint4 fill for winner=-1 (rocclr fillBuffer measured 107 GB/s /
//    39 us on 4 MB -- pathological). Mask needs no init: mask_kernel fully
//    overwrites every word.
//  - 7 chunks n/32,n/32,n/16,n/8,n/8,n/4,3n/8: expected atomics ~0.89M
//    (vs 4M naive, ~1.03M round 4).
//
// Inputs: d_in[0] positions (N*3 f32), d_in[1] colors (N*3 f32),
//         d_in[2] camera_pose (16 f32), d_in[3] intrinsics (9 f32),
//         d_in[4] H (1 int), d_in[5] W (1 int)
// Output: (1,3,H,W) f32 flat.

__global__ void fill_ff_kernel(uint4* __restrict__ p, int n4) {
    int i = blockIdx.x * blockDim.x + threadIdx.x;
    uint4 v = make_uint4(0xFFFFFFFFu, 0xFFFFFFFFu, 0xFFFFFFFFu, 0xFFFFFFFFu);
    for (; i < n4; i += gridDim.x * blockDim.x) p[i] = v;
}

__global__ void proj_kernel(const float* __restrict__ pos,
                            const float* __restrict__ pose,
                            const float* __restrict__ intr,
                            const int* __restrict__ Hp,
                            const int* __restrict__ Wp,
                            int* __restrict__ winner,
                            const unsigned* __restrict__ mask,
                            int use_mask, int start, int end) {
    int i = start + blockIdx.x * blockDim.x + threadIdx.x;
    if (i >= end) return;

    float px = pos[3 * i + 0];
    float py = pos[3 * i + 1];
    float pz = pos[3 * i + 2];

    // pc = R * p + t
    float x = pose[0] * px + pose[1] * py + pose[2]  * pz + pose[3];
    float y = pose[4] * px + pose[5] * py + pose[6]  * pz + pose[7];
    float z = pose[8] * px + pose[9] * py + pose[10] * pz + pose[11];

    float fx = intr[0], cx = intr[2];
    float fy = intr[4], cy = intr[5];

    float u = fx * x / z + cx;
    float v = fy * y / z + cy;

    int xi = (int)u;   // trunc toward zero == numpy astype(int32)
    int yi = (int)v;

    int W = *Wp, H = *Hp;
    if (xi >= 0 && xi < W && yi >= 0 && yi < H) {
        int pix = yi * W + xi;
        if (use_mask && ((mask[pix >> 5] >> (pix & 31)) & 1u)) return; // settled
        atomicMax(&winner[pix], i);
    }
}

// coverage bitmask: bit p = (winner[p] >= 0). Fully overwrites every word.
__global__ void mask_kernel(const int* __restrict__ winner,
                            unsigned* __restrict__ mask,
                            int HW, int maskWords) {
    int p = blockIdx.x * blockDim.x + threadIdx.x;
    bool pred = (p < HW) && (winner[p] >= 0);
    unsigned long long b = __ballot(pred);
    int lane = threadIdx.x & 63;
    if (lane == 0) {
        int base = (blockIdx.x * blockDim.x + (threadIdx.x & ~63)) >> 5;
        if (base < maskWords)     mask[base]     = (unsigned)b;
        if (base + 1 < maskWords) mask[base + 1] = (unsigned)(b >> 32);
    }
}

__global__ void paint_kernel(const int* __restrict__ winner,
                             const float* __restrict__ colors,
                             float* __restrict__ out,
                             int HW) {
    int p = blockIdx.x * blockDim.x + threadIdx.x;
    if (p >= HW) return;

    int w = winner[p];
    float r = 0.0f, g = 0.0f, b = 0.0f;
    if (w >= 0) {
        r = colors[3 * w + 0];
        g = colors[3 * w + 1];
        b = colors[3 * w + 2];
        r = fminf(fmaxf(r, 0.0f), 1.0f);
        g = fminf(fmaxf(g, 0.0f), 1.0f);
        b = fminf(fmaxf(b, 0.0f), 1.0f);
    }
    out[p] = r;
    out[HW + p] = g;
    out[2 * HW + p] = b;
}

extern "C" void kernel_launch(void* const* d_in, const int* in_sizes, int n_in,
                              void* d_out, int out_size, void* d_ws, size_t ws_size,
                              hipStream_t stream) {
    const float* positions = (const float*)d_in[0];
    const float* colors    = (const float*)d_in[1];
    const float* pose      = (const float*)d_in[2];
    const float* intr      = (const float*)d_in[3];
    const int*   Hp        = (const int*)d_in[4];
    const int*   Wp        = (const int*)d_in[5];
    float* out = (float*)d_out;

    int n  = in_sizes[0] / 3;       // number of points
    int HW = out_size / 3;          // H*W pixels

    int* winner = (int*)d_ws;
    int maskWords = (HW + 31) / 32;
    unsigned* mask = (unsigned*)(winner + HW);
    size_t need = (size_t)HW * sizeof(int) + (size_t)maskWords * sizeof(unsigned);

    const int block = 256;

    if (ws_size < need || n < 4096 || (HW & 3)) {
        // Fallback: memset winner, single full atomic pass, no mask.
        hipMemsetAsync(winner, 0xFF, (size_t)HW * sizeof(int), stream);
        int grid = (n + block - 1) / block;
        proj_kernel<<<grid, block, 0, stream>>>(positions, pose, intr, Hp, Wp,
                                                winner, (const unsigned*)0, 0,
                                                0, n);
    } else {
        // winner = -1 via vector fill (mask needs no init: fully rebuilt).
        int n4 = HW / 4;   // HW ints == HW/4 uint4s
        int fgrid = min((n4 + block - 1) / block, 2048);
        fill_ff_kernel<<<fgrid, block, 0, stream>>>((uint4*)winner, n4);

        // Descending chunks: n/32, n/32, n/16, n/8, n/8, n/4, 3n/8.
        long long ln = n;
        int bounds[8];
        bounds[0] = n;
        bounds[1] = (int)(ln * 31 / 32);
        bounds[2] = (int)(ln * 30 / 32);
        bounds[3] = (int)(ln * 28 / 32);
        bounds[4] = (int)(ln * 24 / 32);
        bounds[5] = (int)(ln * 20 / 32);
        bounds[6] = (int)(ln * 12 / 32);
        bounds[7] = 0;

        int maskGrid = (HW + block - 1) / block;
        for (int k = 0; k < 7; ++k) {
            int end = bounds[k], start = bounds[k + 1];
            int cnt = end - start;
            if (cnt <= 0) continue;
            int grid = (cnt + block - 1) / block;
            proj_kernel<<<grid, block, 0, stream>>>(positions, pose, intr, Hp, Wp,
                                                    winner, mask, (k > 0) ? 1 : 0,
                                                    start, end);
            if (k < 6) {
                mask_kernel<<<maskGrid, block, 0, stream>>>(winner, mask, HW,
                                                            maskWords);
            }
        }
    }

    int grid2 = (HW + block - 1) / block;
    paint_kernel<<<grid2, block, 0, stream>>>(winner, colors, out, HW);
}